// Round 10
// baseline (290.468 us; speedup 1.0000x reference)
//
#include <hip/hip_runtime.h>
#include <math.h>

#define HH 128
#define WW 128
#define HW 16384
#define NLINES 49152
#define KJ 300
#define SENT 90000
#define THRESHV 0.008f
#define CAND_CAP 4096
#define BITWORDS 2816   // ceil(90000/32) = 2816 = 256*11

typedef __attribute__((ext_vector_type(8))) short bf16x8;
typedef __attribute__((ext_vector_type(4))) float f32x4;

__device__ __forceinline__ float sigm(float x){ return 1.0f/(1.0f+expf(-x)); }

__device__ __forceinline__ short tobf(float f){
  unsigned u = __float_as_uint(f);
  unsigned r = u + 0x7FFFu + ((u >> 16) & 1u);
  return (short)(r >> 16);
}
__device__ __forceinline__ float bflo(unsigned u){ return __uint_as_float(u << 16); }
__device__ __forceinline__ float bfhi(unsigned u){ return __uint_as_float(u & 0xFFFF0000u); }

#define GLOAD_LDS16(g, l) \
  __builtin_amdgcn_global_load_lds((const __attribute__((address_space(1))) void*)(g), \
                                   (__attribute__((address_space(3))) void*)(l), 16, 0, 0)

__device__ __forceinline__ float jloc_at(const float* hm, int idx){
  float h5 = hm[5*HW + idx], h6 = hm[6*HW + idx];
  float mx = fmaxf(h5,h6);
  float e5 = expf(h5-mx), e6 = expf(h6-mx);
  return e6/(e5+e6);
}

// ---- 1. fused front: prep + LDS-NMS | tcast | fc1 cast | zero d_out ----
__global__ __launch_bounds__(256) void k_front(const float* __restrict__ hm,
    const float* __restrict__ feat, const float* __restrict__ fc1w,
    float* __restrict__ lines, unsigned long long* __restrict__ cand,
    int* __restrict__ cand_count, short* __restrict__ featT, short* __restrict__ fc1b16,
    float* __restrict__ outZero){
  __shared__ float tile[32][33];
  __shared__ float jl[4][128];
  int b = blockIdx.x, t = threadIdx.x;
  if (b < 64){
    // ---- HAFM line decode (2 rows per block) ----
    int i = b*256 + t;
    float h0 = hm[i], h1 = hm[HW+i], h2 = hm[2*HW+i], h3 = hm[3*HW+i], h4 = hm[4*HW+i];
    float a0 = sigm(h0), a1 = sigm(h1), a2 = sigm(h2);
    float dist = sigm(h3), bias = sigm(h4);
    const float PI = 3.14159265358979323846f;
    float ang0 = (a0-0.5f)*(2.0f*PI);
    float c0 = cosf(ang0), s0 = sinf(ang0);
    float t1 = tanf(a1*(0.5f*PI));
    float t2 = tanf(-a2*(0.5f*PI));
    int y = i >> 7, x = i & 127;
    float fx = (float)x, fy = (float)y;
    #pragma unroll
    for (int c=0;c<3;c++){
      float d = fminf(fmaxf(dist + bias*(float)(c-1), 0.0f), 1.0f);
      float ds = d*5.0f;
      float x1 = fminf(fmaxf((c0 - s0*t1)*ds + fx, 0.0f), 127.0f);
      float y1 = fminf(fmaxf((s0 + c0*t1)*ds + fy, 0.0f), 127.0f);
      float x2 = fminf(fmaxf((c0 - s0*t2)*ds + fx, 0.0f), 127.0f);
      float y2 = fminf(fmaxf((s0 + c0*t2)*ds + fy, 0.0f), 127.0f);
      ((float4*)lines)[c*HW + i] = make_float4(x1,y1,x2,y2);
    }
    // ---- jloc tile rows 2b-1 .. 2b+2, identical formula per pixel ----
    int y0 = 2*b;
    #pragma unroll
    for (int idx = t; idx < 512; idx += 256){
      int r = idx >> 7, xx = idx & 127;
      int yy = y0 - 1 + r;
      jl[r][xx] = (yy >= 0 && yy < HH) ? jloc_at(hm, yy*WW + xx) : -1e30f;
    }
    __syncthreads();
    int lr = 1 + (t >> 7);
    float v = jl[lr][x];
    float m = v;
    #pragma unroll
    for (int dy=-1; dy<=1; dy++){
      #pragma unroll
      for (int dx=-1; dx<=1; dx++){
        int nx = x + dx; if (nx < 0 || nx >= WW) continue;
        m = fmaxf(m, jl[lr+dy][nx]);
      }
    }
    if (v == m && v > THRESHV){
      int pos = atomicAdd(cand_count, 1);
      if (pos < CAND_CAP){
        unsigned int vb = __float_as_uint(v);
        cand[pos] = ((unsigned long long)vb << 32) | (unsigned long long)(0xFFFFFFFFu - (unsigned)i);
      }
    }
  } else if (b < 64 + 4096){
    // ---- transpose-cast features [256,HW] fp32 -> featT [HW,256] bf16 ----
    int idx = b - 64;
    int p0 = (idx & 511) * 32, c0 = (idx >> 9) * 32;
    int c  = t >> 3;
    int p4 = (t & 7) * 4;
    float4 v = *(const float4*)&feat[(size_t)(c0 + c)*HW + p0 + p4];
    tile[c][p4+0] = v.x; tile[c][p4+1] = v.y; tile[c][p4+2] = v.z; tile[c][p4+3] = v.w;
    __syncthreads();
    int p  = t >> 3;
    int cg = (t & 7) * 4;
    ushort4 o;
    o.x = (unsigned short)tobf(tile[cg+0][p]);
    o.y = (unsigned short)tobf(tile[cg+1][p]);
    o.z = (unsigned short)tobf(tile[cg+2][p]);
    o.w = (unsigned short)tobf(tile[cg+3][p]);
    *(ushort4*)&featT[(size_t)(p0 + p)*256 + c0 + cg] = o;
  } else if (b < 4288){
    int j = (b - 4160)*256 + t;   // < 32768
    fc1b16[j] = tobf(fc1w[j]);
  } else {
    // ---- zero d_out: 240 blocks x 256 threads x float4 = 245760 floats ----
    int j = (b - 4288)*256 + t;
    ((float4*)outZero)[j] = make_float4(0.f,0.f,0.f,0.f);
  }
}

// ---------------- 2. fused mid: topk(1 blk) | LOI GEMM (256 blks) ----------------
__global__ __launch_bounds__(1024) void k_mid(
    const unsigned long long* __restrict__ cand, const int* __restrict__ cand_count,
    const float* __restrict__ hm, float* __restrict__ junc,
    const short* __restrict__ featT, const short* __restrict__ fc1b16,
    const float* __restrict__ fc1b, short* __restrict__ loi){
  __shared__ __align__(16) char smem[CAND_CAP*8];   // 32 KB union
  int b = blockIdx.x, t = threadIdx.x;
  if (b == 0){
    // ---- bitonic top-K ----
    unsigned long long* s = (unsigned long long*)smem;
    int count = *cand_count; if (count > CAND_CAP) count = CAND_CAP;
    int n2 = 512;
    while (n2 < count) n2 <<= 1;
    for (int i=t; i<n2; i+=1024) s[i] = (i < count) ? cand[i] : 0ull;
    __syncthreads();
    for (int k=2; k<=n2; k<<=1){
      for (int j=k>>1; j>0; j>>=1){
        for (int i=t; i<n2; i+=1024){
          int ixj = i ^ j;
          if (ixj > i){
            unsigned long long a = s[i], bb = s[ixj];
            bool desc = ((i & k) == 0);
            if (desc ? (a < bb) : (a > bb)){ s[i] = bb; s[ixj] = a; }
          }
        }
        __syncthreads();
      }
    }
    if (t < KJ){
      float jx = 1e6f, jy = 1e6f;
      if (t < count){
        unsigned idx = 0xFFFFFFFFu - (unsigned)(s[t] & 0xFFFFFFFFull);
        int yy = (int)(idx >> 7), xx = (int)(idx & 127u);
        jx = (float)xx + sigm(hm[7*HW + idx]);
        jy = (float)yy + sigm(hm[8*HW + idx]);
      }
      junc[2*t] = jx; junc[2*t+1] = jy;
    }
  } else {
    // ---- LOI GEMM: featT[HW,256] @ fc1w[128,256]^T -> loi[HW,128] bf16 ----
    if (t >= 256) return;
    short* As = (short*)smem;            // 8 KB
    short* Bs = (short*)(smem + 8192);   // 16 KB
    int rb = (b - 1) * 64;
    int lane = t & 63, wave = t >> 6;
    int l16 = lane & 15, quad = lane >> 4;
    int srow = lane >> 3, schunk = (lane & 7) ^ srow;
    f32x4 acc[8];
    #pragma unroll
    for (int g=0; g<8; g++) acc[g] = (f32x4){0,0,0,0};
    for (int k0=0; k0<256; k0+=64){
      #pragma unroll
      for (int i=0; i<2; i++){
        int r0 = wave*16 + i*8;
        GLOAD_LDS16(featT + (size_t)(rb + r0 + srow)*256 + k0 + schunk*8, &As[r0*64]);
      }
      #pragma unroll
      for (int i=0; i<4; i++){
        int r0 = wave*32 + i*8;
        GLOAD_LDS16(fc1b16 + (size_t)(r0 + srow)*256 + k0 + schunk*8, &Bs[r0*64]);
      }
      __syncthreads();
      #pragma unroll
      for (int s2=0; s2<2; s2++){
        int slot = (s2*4 + quad) ^ (l16 & 7);
        bf16x8 a = *(const bf16x8*)&As[(wave*16 + l16)*64 + slot*8];
        #pragma unroll
        for (int g=0; g<8; g++){
          bf16x8 bv = *(const bf16x8*)&Bs[(g*16 + l16)*64 + slot*8];
          acc[g] = __builtin_amdgcn_mfma_f32_16x16x32_bf16(a, bv, acc[g], 0, 0, 0);
        }
      }
      __syncthreads();
    }
    int rowbase = rb + wave*16 + quad*4;
    #pragma unroll
    for (int g=0; g<8; g++){
      int col = g*16 + l16;
      float bs = fc1b[col];
      #pragma unroll
      for (int r=0; r<4; r++)
        loi[(size_t)(rowbase + r)*128 + col] = tobf(acc[g][r] + bs);
    }
  }
}

// ---- 3. match -> global bitmap | w1/w2 cast | LAST block: unique scan ----
// Completion fence is tid0-only (mlp2-proven pattern; r6's regression was
// per-THREAD fences: 1.1M fences = 290us. 4288 tid0 fences ~= 1us.)
__global__ __launch_bounds__(256) void k_match(const float* __restrict__ lines,
    const float* __restrict__ junc, unsigned* __restrict__ bm,
    int* __restrict__ mdone, int* __restrict__ uid_list, int* __restrict__ mcount,
    const float* __restrict__ w1, const float* __restrict__ w2,
    short* __restrict__ w1b, short* __restrict__ w2b){
  __shared__ float jx[KJ], jy[KJ];
  __shared__ int wsum[4];
  __shared__ int lastflag;
  int b = blockIdx.x, t = threadIdx.x;
  if (b < 192){
    for (int k=t; k<KJ; k+=256){ jx[k] = junc[2*k]; jy[k] = junc[2*k+1]; }
    __syncthreads();
    int n = b*256 + t;
    float4 L = ((const float4*)lines)[n];
    float b1 = 1e30f, b2 = 1e30f; int j1 = 0, j2 = 0;
    #pragma unroll 4
    for (int k=0; k<KJ; k++){
      float dx1 = jx[k]-L.x, dy1 = jy[k]-L.y;
      float d1 = dx1*dx1 + dy1*dy1;
      float dx2 = jx[k]-L.z, dy2 = jy[k]-L.w;
      float d2 = dx2*dx2 + dy2*dy2;
      if (d1 < b1){ b1 = d1; j1 = k; }
      if (d2 < b2){ b2 = d2; j2 = k; }
    }
    int lo = min(j1,j2), hi = max(j1,j2);
    if (lo < hi){
      int id = lo*KJ + hi;
      atomicOr(&bm[id >> 5], 1u << (id & 31));
    }
  } else {
    int j = (b - 192)*256 + t;   // < 1M
    w1b[j] = tobf(w1[j]);
    w2b[j] = tobf(w2[j]);
  }
  // ---- completion: last block performs the unique scan ----
  __syncthreads();
  if (t == 0){
    __threadfence();
    int old = atomicAdd(mdone, 1);
    lastflag = (old == (int)gridDim.x - 1) ? 1 : 0;
  }
  __syncthreads();
  if (!lastflag) return;
  unsigned w[11];
  int local = 0;
  #pragma unroll
  for (int i=0; i<11; i++){
    w[i] = atomicOr(&bm[t*11 + i], 0u);   // coherent read
    local += __popc(w[i]);
  }
  int v = local;
  #pragma unroll
  for (int d=1; d<64; d<<=1){
    int nv = __shfl_up(v, d, 64);
    if ((t & 63) >= d) v += nv;
  }
  if ((t & 63) == 63) wsum[t >> 6] = v;
  __syncthreads();
  if (t < 4){
    int x = wsum[t];
    #pragma unroll
    for (int d=1; d<4; d<<=1){
      int nv = __shfl_up(x, d, 4);
      if (t >= d) x += nv;
    }
    wsum[t] = x;
  }
  __syncthreads();
  int base = v - local + ((t >> 6) ? wsum[(t >> 6) - 1] : 0);
  #pragma unroll
  for (int i=0; i<11; i++){
    unsigned bits = w[i];
    while (bits){
      int bb = __ffs(bits) - 1;
      uid_list[base++] = (t*11 + i)*32 + bb;
      bits &= bits - 1;
    }
  }
  if (t == 255) *mcount = wsum[3];
}

// ---- 4. sampling, 2 lines per block-iteration (+ coords write) ----
__global__ __launch_bounds__(256) void k_sample(float* __restrict__ out,
    const int* __restrict__ uid_list, const float* __restrict__ junc,
    const short* __restrict__ loi, const int* __restrict__ mcount,
    short* __restrict__ fbuf, float* __restrict__ logit, int* __restrict__ cnt,
    int ncnt, int chunk0, int chunk){
  __shared__ int4   sOffs[2][32];
  __shared__ float4 sWts[2][32];
  int M = *mcount;
  int t = threadIdx.x;
  if (t == 0 && blockIdx.x < ncnt) cnt[blockIdx.x] = 0;
  int q  = t >> 6;
  int c2 = (t & 63) << 1;
  int lim = M - chunk0; if (lim > chunk) lim = chunk;
  for (int l0 = blockIdx.x*2; l0 < lim; l0 += gridDim.x*2){
    __syncthreads();          // protect LDS from previous iteration's readers
    if (t < 64){
      int pair = t >> 5, s = t & 31;
      int l = l0 + pair;
      if (l < lim){
        int r = chunk0 + l;
        int id = uid_list[r];
        int lo = id / KJ, hi = id % KJ;
        float2 P1 = ((const float2*)junc)[lo];
        float2 P2 = ((const float2*)junc)[hi];
        if (s == 0){
          ((float4*)out)[r] = make_float4(P1.x, P1.y, P2.x, P2.y);
          logit[l] = 0.0f;
        }
        float tt = (float)s * (1.0f/31.0f);
        float px = P1.x*tt + P2.x*(1.0f-tt);
        float py = P1.y*tt + P2.y*(1.0f-tt);
        px = fminf(fmaxf(px, 0.0f), 127.0f);
        py = fminf(fmaxf(py, 0.0f), 127.0f);
        float x0 = floorf(px), y0 = floorf(py);
        int x0i = (int)x0, y0i = (int)y0;
        int x1i = min(x0i+1, 127), y1i = min(y0i+1, 127);
        float wx = px - x0, wy = py - y0;
        sOffs[pair][s] = make_int4((y0i*WW + x0i)*128, (y0i*WW + x1i)*128,
                                   (y1i*WW + x0i)*128, (y1i*WW + x1i)*128);
        sWts[pair][s]  = make_float4((1.0f-wx)*(1.0f-wy), wx*(1.0f-wy),
                                     (1.0f-wx)*wy,        wx*wy);
      }
    }
    __syncthreads();
    #pragma unroll
    for (int pair=0; pair<2; pair++){
      int l = l0 + pair;
      if (l >= lim) break;
      float gl0=-1e30f, gl1=-1e30f, gh0=-1e30f, gh1=-1e30f;
      #pragma unroll
      for (int j=0; j<8; j++){
        int s = q*8 + j;
        int4 o   = sOffs[pair][s];
        float4 w = sWts[pair][s];
        unsigned u00 = *(const unsigned*)&loi[o.x + c2];
        unsigned u01 = *(const unsigned*)&loi[o.y + c2];
        unsigned u10 = *(const unsigned*)&loi[o.z + c2];
        unsigned u11 = *(const unsigned*)&loi[o.w + c2];
        float vlo = w.x*bflo(u00) + w.y*bflo(u01) + w.z*bflo(u10) + w.w*bflo(u11);
        float vhi = w.x*bfhi(u00) + w.y*bfhi(u01) + w.z*bfhi(u10) + w.w*bfhi(u11);
        if (j < 4){ gl0 = fmaxf(gl0, vlo); gh0 = fmaxf(gh0, vhi); }
        else      { gl1 = fmaxf(gl1, vlo); gh1 = fmaxf(gh1, vhi); }
      }
      unsigned plo = ((unsigned)(unsigned short)tobf(gl0)) | (((unsigned)(unsigned short)tobf(gl1)) << 16);
      unsigned phi = ((unsigned)(unsigned short)tobf(gh0)) | (((unsigned)(unsigned short)tobf(gh1)) << 16);
      *(unsigned*)&fbuf[(size_t)l*1024 + c2*8 + q*2]     = plo;
      *(unsigned*)&fbuf[(size_t)l*1024 + (c2+1)*8 + q*2] = phi;
    }
  }
}

// ---------------- 5. 64x128-tile MFMA MLP GEMM ----------------
// MODE 0: Hout bf16 = relu(C + bias)
// MODE 2: logit += relu(C + bias).w3 ; last col-block applies sigmoid -> out
template<int MODE>
__global__ __launch_bounds__(256) void k_mlp(const short* __restrict__ A,
    const short* __restrict__ B, const float* __restrict__ bias,
    short* __restrict__ Hout, const float* __restrict__ w3,
    const float* __restrict__ b3, float* __restrict__ logit,
    int* __restrict__ cnt, const int* __restrict__ mcount,
    int chunk0, float* __restrict__ outScore){
  int M = *mcount;
  int rb = blockIdx.x * 64;
  if (chunk0 + rb >= M) return;
  int cb = blockIdx.y * 128;
  __shared__ short As[64*64];    // 8 KB
  __shared__ short Bs[128*64];   // 16 KB
  __shared__ int sflag;
  int lane = threadIdx.x & 63, wave = threadIdx.x >> 6;
  int l16 = lane & 15, quad = lane >> 4;
  int srow = lane >> 3, schunk = (lane & 7) ^ srow;
  f32x4 acc[8];
  #pragma unroll
  for (int g=0; g<8; g++) acc[g] = (f32x4){0,0,0,0};
  for (int k0=0; k0<1024; k0+=64){
    #pragma unroll
    for (int i=0; i<2; i++){
      int r0 = wave*16 + i*8;
      GLOAD_LDS16(A + (size_t)(rb + r0 + srow)*1024 + k0 + schunk*8, &As[r0*64]);
    }
    #pragma unroll
    for (int i=0; i<4; i++){
      int r0 = wave*32 + i*8;
      GLOAD_LDS16(B + (size_t)(cb + r0 + srow)*1024 + k0 + schunk*8, &Bs[r0*64]);
    }
    __syncthreads();
    #pragma unroll
    for (int s=0; s<2; s++){
      int slot = (s*4 + quad) ^ (l16 & 7);
      bf16x8 a = *(const bf16x8*)&As[(wave*16 + l16)*64 + slot*8];
      #pragma unroll
      for (int g=0; g<8; g++){
        bf16x8 bv = *(const bf16x8*)&Bs[(g*16 + l16)*64 + slot*8];
        acc[g] = __builtin_amdgcn_mfma_f32_16x16x32_bf16(a, bv, acc[g], 0, 0, 0);
      }
    }
    __syncthreads();
  }
  int rowbase = rb + wave*16 + quad*4;
  if (MODE == 0){
    #pragma unroll
    for (int g=0; g<8; g++){
      int col = cb + g*16 + l16;
      float bs = bias[col];
      #pragma unroll
      for (int r=0; r<4; r++)
        Hout[(size_t)(rowbase + r)*1024 + col] = tobf(fmaxf(acc[g][r] + bs, 0.0f));
    }
  } else {
    float p0[4] = {0,0,0,0};
    #pragma unroll
    for (int g=0; g<8; g++){
      int col = cb + g*16 + l16;
      float bs = bias[col], wv = w3[col];
      #pragma unroll
      for (int r=0; r<4; r++)
        p0[r] += fmaxf(acc[g][r] + bs, 0.0f) * wv;
    }
    #pragma unroll
    for (int r=0; r<4; r++){
      #pragma unroll
      for (int m=1; m<16; m<<=1)
        p0[r] += __shfl_xor(p0[r], m, 16);
    }
    if (l16 == 0){
      #pragma unroll
      for (int r=0; r<4; r++)
        atomicAdd(&logit[rowbase + r], p0[r]);
    }
    __syncthreads();
    if (threadIdx.x == 0){
      __threadfence();                       // one fence per block (tid 0 only!)
      int old = atomicAdd(&cnt[blockIdx.x], 1);
      sflag = (old == 7) ? 1 : 0;
    }
    __syncthreads();
    if (sflag){
      __threadfence();
      if (threadIdx.x < 64){
        int row = rb + threadIdx.x;
        int rg = chunk0 + row;
        if (rg < M){
          float lg = atomicAdd(&logit[row], 0.0f) + b3[0];  // coherent read
          outScore[4*NLINES + rg] = 1.0f/(1.0f + expf(-lg));
        }
      }
    }
  }
}

extern "C" void kernel_launch(void* const* d_in, const int* in_sizes, int n_in,
                              void* d_out, int out_size, void* d_ws, size_t ws_size,
                              hipStream_t stream){
  const float* features = (const float*)d_in[0];
  const float* heatmaps = (const float*)d_in[1];
  const float* fc1_w    = (const float*)d_in[2];
  const float* fc1_b    = (const float*)d_in[3];
  const float* w1       = (const float*)d_in[4];
  const float* b1       = (const float*)d_in[5];
  const float* w2       = (const float*)d_in[6];
  const float* b2       = (const float*)d_in[7];
  const float* w3       = (const float*)d_in[8];
  const float* b3       = (const float*)d_in[9];
  float* out = (float*)d_out;

  char* ws = (char*)d_ws;
  size_t off = 0;
  auto alloc = [&](size_t bytes) -> void* {
    void* p = ws + off;
    off = (off + bytes + 255) & ~(size_t)255;
    return p;
  };
  float* lines     = (float*)alloc((size_t)NLINES*16);
  unsigned long long* cand = (unsigned long long*)alloc(CAND_CAP*8);
  // --- zero-init region: cand_count + mdone + bitmap (one async memset) ---
  int*      cand_count = (int*)alloc(4);
  int*      mdone      = (int*)alloc(4);
  unsigned* bitmap     = (unsigned*)alloc(BITWORDS*4);
  size_t zlen = (size_t)((char*)(bitmap + BITWORDS) - (char*)cand_count);
  float* junc      = (float*)alloc(KJ*2*4);
  int*   uid_list  = (int*)alloc((size_t)45056*4);
  int*   mcount    = (int*)alloc(4);
  int*   cnt       = (int*)alloc((45056/64)*4);
  short* loi       = (short*)alloc((size_t)HW*128*2);
  short* featT     = (short*)alloc((size_t)HW*256*2);
  short* fc1b16    = (short*)alloc((size_t)128*256*2);
  short* w1b       = (short*)alloc((size_t)1024*1024*2);
  short* w2b       = (short*)alloc((size_t)1024*1024*2);
  size_t fixed = off;

  // M <= KJ*(KJ-1)/2 = 44850 -> 45056 rows (64-aligned) max
  const int chunk_opts[4] = {45056, 22528, 11264, 5632};
  int CHUNK = 5632;
  for (int ci=0; ci<4; ci++){
    size_t need = fixed + (size_t)chunk_opts[ci]*1024*2*2 + (size_t)chunk_opts[ci]*4 + 1024;
    if (need <= ws_size){ CHUNK = chunk_opts[ci]; break; }
  }
  short* fbuf  = (short*)alloc((size_t)CHUNK*1024*2);
  short* h1buf = (short*)alloc((size_t)CHUNK*1024*2);
  float* logit = (float*)alloc((size_t)CHUNK*4);

  hipMemsetAsync(cand_count, 0, zlen, stream);
  k_front<<<4528, 256, 0, stream>>>(heatmaps, features, fc1_w, lines, cand,
                                    cand_count, featT, fc1b16, out);
  k_mid  <<<257, 1024, 0, stream>>>(cand, cand_count, heatmaps, junc, featT,
                                    fc1b16, fc1_b, loi);
  k_match<<<4288, 256, 0, stream>>>(lines, junc, bitmap, mdone, uid_list, mcount,
                                    w1, w2, w1b, w2b);

  int nchunk = (45056 + CHUNK - 1) / CHUNK;
  for (int ci=0; ci<nchunk; ci++){
    int chunk0 = ci * CHUNK;
    k_sample<<<1024, 256, 0, stream>>>(out, uid_list, junc, loi, mcount, fbuf,
                                       logit, cnt, CHUNK/64, chunk0, CHUNK);
    dim3 g1(CHUNK/64, 8);
    k_mlp<0><<<g1, 256, 0, stream>>>(fbuf, w1b, b1, h1buf, nullptr, nullptr,
                                     nullptr, nullptr, mcount, chunk0, nullptr);
    k_mlp<2><<<g1, 256, 0, stream>>>(h1buf, w2b, b2, nullptr, w3, b3,
                                     logit, cnt, mcount, chunk0, out);
  }
}

// Round 11
// 199.551 us; speedup vs baseline: 1.4556x; 1.4556x over previous
//
#include <hip/hip_runtime.h>
#include <math.h>

#define HH 128
#define WW 128
#define HW 16384
#define NLINES 49152
#define KJ 300
#define SENT 90000
#define THRESHV 0.008f
#define CAND_CAP 4096
#define BITWORDS 2816   // ceil(90000/32)

typedef __attribute__((ext_vector_type(8))) short bf16x8;
typedef __attribute__((ext_vector_type(4))) float f32x4;

__device__ __forceinline__ float sigm(float x){ return 1.0f/(1.0f+expf(-x)); }

__device__ __forceinline__ short tobf(float f){
  unsigned u = __float_as_uint(f);
  unsigned r = u + 0x7FFFu + ((u >> 16) & 1u);
  return (short)(r >> 16);
}
__device__ __forceinline__ float bflo(unsigned u){ return __uint_as_float(u << 16); }
__device__ __forceinline__ float bfhi(unsigned u){ return __uint_as_float(u & 0xFFFF0000u); }

#define GLOAD_LDS16(g, l) \
  __builtin_amdgcn_global_load_lds((const __attribute__((address_space(1))) void*)(g), \
                                   (__attribute__((address_space(3))) void*)(l), 16, 0, 0)

__device__ __forceinline__ float jloc_at(const float* hm, int idx){
  float h5 = hm[5*HW + idx], h6 = hm[6*HW + idx];
  float mx = fmaxf(h5,h6);
  float e5 = expf(h5-mx), e6 = expf(h6-mx);
  return e6/(e5+e6);
}

// ---- 1. fused front: prep + LDS-NMS | tcast | fc1 cast | zero d_out ----
__global__ __launch_bounds__(256) void k_front(const float* __restrict__ hm,
    const float* __restrict__ feat, const float* __restrict__ fc1w,
    float* __restrict__ lines, unsigned long long* __restrict__ cand,
    int* __restrict__ cand_count, short* __restrict__ featT, short* __restrict__ fc1b16,
    float* __restrict__ outZero){
  __shared__ float tile[32][33];
  __shared__ float jl[4][128];
  int b = blockIdx.x, t = threadIdx.x;
  if (b < 64){
    // ---- HAFM line decode (2 rows per block) ----
    int i = b*256 + t;
    float h0 = hm[i], h1 = hm[HW+i], h2 = hm[2*HW+i], h3 = hm[3*HW+i], h4 = hm[4*HW+i];
    float a0 = sigm(h0), a1 = sigm(h1), a2 = sigm(h2);
    float dist = sigm(h3), bias = sigm(h4);
    const float PI = 3.14159265358979323846f;
    float ang0 = (a0-0.5f)*(2.0f*PI);
    float c0 = cosf(ang0), s0 = sinf(ang0);
    float t1 = tanf(a1*(0.5f*PI));
    float t2 = tanf(-a2*(0.5f*PI));
    int y = i >> 7, x = i & 127;
    float fx = (float)x, fy = (float)y;
    #pragma unroll
    for (int c=0;c<3;c++){
      float d = fminf(fmaxf(dist + bias*(float)(c-1), 0.0f), 1.0f);
      float ds = d*5.0f;
      float x1 = fminf(fmaxf((c0 - s0*t1)*ds + fx, 0.0f), 127.0f);
      float y1 = fminf(fmaxf((s0 + c0*t1)*ds + fy, 0.0f), 127.0f);
      float x2 = fminf(fmaxf((c0 - s0*t2)*ds + fx, 0.0f), 127.0f);
      float y2 = fminf(fmaxf((s0 + c0*t2)*ds + fy, 0.0f), 127.0f);
      ((float4*)lines)[c*HW + i] = make_float4(x1,y1,x2,y2);
    }
    // ---- jloc tile rows 2b-1 .. 2b+2, identical formula per pixel ----
    int y0 = 2*b;
    #pragma unroll
    for (int idx = t; idx < 512; idx += 256){
      int r = idx >> 7, xx = idx & 127;
      int yy = y0 - 1 + r;
      jl[r][xx] = (yy >= 0 && yy < HH) ? jloc_at(hm, yy*WW + xx) : -1e30f;
    }
    __syncthreads();
    int lr = 1 + (t >> 7);
    float v = jl[lr][x];
    float m = v;
    #pragma unroll
    for (int dy=-1; dy<=1; dy++){
      #pragma unroll
      for (int dx=-1; dx<=1; dx++){
        int nx = x + dx; if (nx < 0 || nx >= WW) continue;
        m = fmaxf(m, jl[lr+dy][nx]);
      }
    }
    if (v == m && v > THRESHV){
      int pos = atomicAdd(cand_count, 1);
      if (pos < CAND_CAP){
        unsigned int vb = __float_as_uint(v);
        cand[pos] = ((unsigned long long)vb << 32) | (unsigned long long)(0xFFFFFFFFu - (unsigned)i);
      }
    }
  } else if (b < 64 + 4096){
    // ---- transpose-cast features [256,HW] fp32 -> featT [HW,256] bf16 ----
    int idx = b - 64;
    int p0 = (idx & 511) * 32, c0 = (idx >> 9) * 32;
    int c  = t >> 3;
    int p4 = (t & 7) * 4;
    float4 v = *(const float4*)&feat[(size_t)(c0 + c)*HW + p0 + p4];
    tile[c][p4+0] = v.x; tile[c][p4+1] = v.y; tile[c][p4+2] = v.z; tile[c][p4+3] = v.w;
    __syncthreads();
    int p  = t >> 3;
    int cg = (t & 7) * 4;
    ushort4 o;
    o.x = (unsigned short)tobf(tile[cg+0][p]);
    o.y = (unsigned short)tobf(tile[cg+1][p]);
    o.z = (unsigned short)tobf(tile[cg+2][p]);
    o.w = (unsigned short)tobf(tile[cg+3][p]);
    *(ushort4*)&featT[(size_t)(p0 + p)*256 + c0 + cg] = o;
  } else if (b < 4288){
    int j = (b - 4160)*256 + t;   // < 32768
    fc1b16[j] = tobf(fc1w[j]);
  } else {
    // ---- zero d_out: 240 blocks x 256 threads x float4 = 245760 floats ----
    int j = (b - 4288)*256 + t;
    ((float4*)outZero)[j] = make_float4(0.f,0.f,0.f,0.f);
  }
}

// ---------------- 2. fused mid: topk(1 blk) | LOI GEMM (256 blks) ----------------
__global__ __launch_bounds__(1024) void k_mid(
    const unsigned long long* __restrict__ cand, const int* __restrict__ cand_count,
    const float* __restrict__ hm, float* __restrict__ junc,
    const short* __restrict__ featT, const short* __restrict__ fc1b16,
    const float* __restrict__ fc1b, short* __restrict__ loi){
  __shared__ __align__(16) char smem[CAND_CAP*8];   // 32 KB union
  int b = blockIdx.x, t = threadIdx.x;
  if (b == 0){
    // ---- bitonic top-K ----
    unsigned long long* s = (unsigned long long*)smem;
    int count = *cand_count; if (count > CAND_CAP) count = CAND_CAP;
    int n2 = 512;
    while (n2 < count) n2 <<= 1;
    for (int i=t; i<n2; i+=1024) s[i] = (i < count) ? cand[i] : 0ull;
    __syncthreads();
    for (int k=2; k<=n2; k<<=1){
      for (int j=k>>1; j>0; j>>=1){
        for (int i=t; i<n2; i+=1024){
          int ixj = i ^ j;
          if (ixj > i){
            unsigned long long a = s[i], bb = s[ixj];
            bool desc = ((i & k) == 0);
            if (desc ? (a < bb) : (a > bb)){ s[i] = bb; s[ixj] = a; }
          }
        }
        __syncthreads();
      }
    }
    if (t < KJ){
      float jx = 1e6f, jy = 1e6f;
      if (t < count){
        unsigned idx = 0xFFFFFFFFu - (unsigned)(s[t] & 0xFFFFFFFFull);
        int yy = (int)(idx >> 7), xx = (int)(idx & 127u);
        jx = (float)xx + sigm(hm[7*HW + idx]);
        jy = (float)yy + sigm(hm[8*HW + idx]);
      }
      junc[2*t] = jx; junc[2*t+1] = jy;
    }
  } else {
    // ---- LOI GEMM: featT[HW,256] @ fc1w[128,256]^T -> loi[HW,128] bf16 ----
    if (t >= 256) return;
    short* As = (short*)smem;            // 8 KB
    short* Bs = (short*)(smem + 8192);   // 16 KB
    int rb = (b - 1) * 64;
    int lane = t & 63, wave = t >> 6;
    int l16 = lane & 15, quad = lane >> 4;
    int srow = lane >> 3, schunk = (lane & 7) ^ srow;
    f32x4 acc[8];
    #pragma unroll
    for (int g=0; g<8; g++) acc[g] = (f32x4){0,0,0,0};
    for (int k0=0; k0<256; k0+=64){
      #pragma unroll
      for (int i=0; i<2; i++){
        int r0 = wave*16 + i*8;
        GLOAD_LDS16(featT + (size_t)(rb + r0 + srow)*256 + k0 + schunk*8, &As[r0*64]);
      }
      #pragma unroll
      for (int i=0; i<4; i++){
        int r0 = wave*32 + i*8;
        GLOAD_LDS16(fc1b16 + (size_t)(r0 + srow)*256 + k0 + schunk*8, &Bs[r0*64]);
      }
      __syncthreads();
      #pragma unroll
      for (int s2=0; s2<2; s2++){
        int slot = (s2*4 + quad) ^ (l16 & 7);
        bf16x8 a = *(const bf16x8*)&As[(wave*16 + l16)*64 + slot*8];
        #pragma unroll
        for (int g=0; g<8; g++){
          bf16x8 bv = *(const bf16x8*)&Bs[(g*16 + l16)*64 + slot*8];
          acc[g] = __builtin_amdgcn_mfma_f32_16x16x32_bf16(a, bv, acc[g], 0, 0, 0);
        }
      }
      __syncthreads();
    }
    int rowbase = rb + wave*16 + quad*4;
    #pragma unroll
    for (int g=0; g<8; g++){
      int col = g*16 + l16;
      float bs = fc1b[col];
      #pragma unroll
      for (int r=0; r<4; r++)
        loi[(size_t)(rowbase + r)*128 + col] = tobf(acc[g][r] + bs);
    }
  }
}

// ---- 3. match -> global bitmap | w1/w2 cast  (ZERO fences anywhere) ----
__global__ __launch_bounds__(256) void k_match(const float* __restrict__ lines,
    const float* __restrict__ junc, unsigned* __restrict__ bm,
    const float* __restrict__ w1, const float* __restrict__ w2,
    short* __restrict__ w1b, short* __restrict__ w2b){
  __shared__ float jx[KJ], jy[KJ];
  int b = blockIdx.x, t = threadIdx.x;
  if (b < 192){
    for (int k=t; k<KJ; k+=256){ jx[k] = junc[2*k]; jy[k] = junc[2*k+1]; }
    __syncthreads();
    int n = b*256 + t;
    float4 L = ((const float4*)lines)[n];
    float b1 = 1e30f, b2 = 1e30f; int j1 = 0, j2 = 0;
    #pragma unroll 4
    for (int k=0; k<KJ; k++){
      float dx1 = jx[k]-L.x, dy1 = jy[k]-L.y;
      float d1 = dx1*dx1 + dy1*dy1;
      float dx2 = jx[k]-L.z, dy2 = jy[k]-L.w;
      float d2 = dx2*dx2 + dy2*dy2;
      if (d1 < b1){ b1 = d1; j1 = k; }
      if (d2 < b2){ b2 = d2; j2 = k; }
    }
    int lo = min(j1,j2), hi = max(j1,j2);
    if (lo < hi){
      int id = lo*KJ + hi;
      atomicOr(&bm[id >> 5], 1u << (id & 31));   // device-scope atomic; kernel boundary gives visibility
    }
  } else {
    int j = (b - 192)*256 + t;   // < 1M
    w1b[j] = tobf(w1[j]);
    w2b[j] = tobf(w2[j]);
  }
}

// ---------------- 4. unique: scan 2816-word global bitmap (1 block) ----------
__global__ __launch_bounds__(1024) void k_unique(const unsigned* __restrict__ bm,
    int* __restrict__ uid_list, int* __restrict__ mcount){
  __shared__ int wsum[16];
  int t = threadIdx.x;
  int w0 = t*3;
  unsigned wv[3];
  int local = 0;
  #pragma unroll
  for (int i=0; i<3; i++){
    int w = w0 + i;
    wv[i] = (w < BITWORDS) ? bm[w] : 0u;
    local += __popc(wv[i]);
  }
  int v = local;
  #pragma unroll
  for (int d=1; d<64; d<<=1){
    int nv = __shfl_up(v, d, 64);
    if ((t & 63) >= d) v += nv;
  }
  if ((t & 63) == 63) wsum[t >> 6] = v;
  __syncthreads();
  if (t < 16){
    int x = wsum[t];
    #pragma unroll
    for (int d=1; d<16; d<<=1){
      int nv = __shfl_up(x, d, 16);
      if (t >= d) x += nv;
    }
    wsum[t] = x;
  }
  __syncthreads();
  int base = v - local + ((t >> 6) ? wsum[(t >> 6) - 1] : 0);
  #pragma unroll
  for (int i=0; i<3; i++){
    unsigned bits = wv[i];
    while (bits){
      int bb = __ffs(bits) - 1;
      uid_list[base++] = (w0 + i)*32 + bb;
      bits &= bits - 1;
    }
  }
  if (t == 1023) *mcount = wsum[15];
}

// ---- 5. sampling, 2 lines per block-iteration (+ coords write) ----
__global__ __launch_bounds__(256) void k_sample(float* __restrict__ out,
    const int* __restrict__ uid_list, const float* __restrict__ junc,
    const short* __restrict__ loi, const int* __restrict__ mcount,
    short* __restrict__ fbuf, float* __restrict__ logit, int chunk0, int chunk){
  __shared__ int4   sOffs[2][32];
  __shared__ float4 sWts[2][32];
  int M = *mcount;
  int t = threadIdx.x;
  int q  = t >> 6;
  int c2 = (t & 63) << 1;
  int lim = M - chunk0; if (lim > chunk) lim = chunk;
  for (int l0 = blockIdx.x*2; l0 < lim; l0 += gridDim.x*2){
    __syncthreads();          // protect LDS from previous iteration's readers
    if (t < 64){
      int pair = t >> 5, s = t & 31;
      int l = l0 + pair;
      if (l < lim){
        int r = chunk0 + l;
        int id = uid_list[r];
        int lo = id / KJ, hi = id % KJ;
        float2 P1 = ((const float2*)junc)[lo];
        float2 P2 = ((const float2*)junc)[hi];
        if (s == 0){
          ((float4*)out)[r] = make_float4(P1.x, P1.y, P2.x, P2.y);
          logit[l] = 0.0f;
        }
        float tt = (float)s * (1.0f/31.0f);
        float px = P1.x*tt + P2.x*(1.0f-tt);
        float py = P1.y*tt + P2.y*(1.0f-tt);
        px = fminf(fmaxf(px, 0.0f), 127.0f);
        py = fminf(fmaxf(py, 0.0f), 127.0f);
        float x0 = floorf(px), y0 = floorf(py);
        int x0i = (int)x0, y0i = (int)y0;
        int x1i = min(x0i+1, 127), y1i = min(y0i+1, 127);
        float wx = px - x0, wy = py - y0;
        sOffs[pair][s] = make_int4((y0i*WW + x0i)*128, (y0i*WW + x1i)*128,
                                   (y1i*WW + x0i)*128, (y1i*WW + x1i)*128);
        sWts[pair][s]  = make_float4((1.0f-wx)*(1.0f-wy), wx*(1.0f-wy),
                                     (1.0f-wx)*wy,        wx*wy);
      }
    }
    __syncthreads();
    #pragma unroll
    for (int pair=0; pair<2; pair++){
      int l = l0 + pair;
      if (l >= lim) break;
      float gl0=-1e30f, gl1=-1e30f, gh0=-1e30f, gh1=-1e30f;
      #pragma unroll
      for (int j=0; j<8; j++){
        int s = q*8 + j;
        int4 o   = sOffs[pair][s];
        float4 w = sWts[pair][s];
        unsigned u00 = *(const unsigned*)&loi[o.x + c2];
        unsigned u01 = *(const unsigned*)&loi[o.y + c2];
        unsigned u10 = *(const unsigned*)&loi[o.z + c2];
        unsigned u11 = *(const unsigned*)&loi[o.w + c2];
        float vlo = w.x*bflo(u00) + w.y*bflo(u01) + w.z*bflo(u10) + w.w*bflo(u11);
        float vhi = w.x*bfhi(u00) + w.y*bfhi(u01) + w.z*bfhi(u10) + w.w*bfhi(u11);
        if (j < 4){ gl0 = fmaxf(gl0, vlo); gh0 = fmaxf(gh0, vhi); }
        else      { gl1 = fmaxf(gl1, vlo); gh1 = fmaxf(gh1, vhi); }
      }
      unsigned plo = ((unsigned)(unsigned short)tobf(gl0)) | (((unsigned)(unsigned short)tobf(gl1)) << 16);
      unsigned phi = ((unsigned)(unsigned short)tobf(gh0)) | (((unsigned)(unsigned short)tobf(gh1)) << 16);
      *(unsigned*)&fbuf[(size_t)l*1024 + c2*8 + q*2]     = plo;
      *(unsigned*)&fbuf[(size_t)l*1024 + (c2+1)*8 + q*2] = phi;
    }
  }
}

// ---------------- 6. 64x128-tile MFMA MLP GEMM (no fences) ----------------
// MODE 0: Hout bf16 = relu(C + bias)
// MODE 2: logit += relu(C + bias).w3  (plain device atomics only)
template<int MODE>
__global__ __launch_bounds__(256) void k_mlp(const short* __restrict__ A,
    const short* __restrict__ B, const float* __restrict__ bias,
    short* __restrict__ Hout, const float* __restrict__ w3,
    float* __restrict__ logit, const int* __restrict__ mcount, int chunk0){
  int M = *mcount;
  int rb = blockIdx.x * 64;
  if (chunk0 + rb >= M) return;
  int cb = blockIdx.y * 128;
  __shared__ short As[64*64];    // 8 KB
  __shared__ short Bs[128*64];   // 16 KB
  int lane = threadIdx.x & 63, wave = threadIdx.x >> 6;
  int l16 = lane & 15, quad = lane >> 4;
  int srow = lane >> 3, schunk = (lane & 7) ^ srow;
  f32x4 acc[8];
  #pragma unroll
  for (int g=0; g<8; g++) acc[g] = (f32x4){0,0,0,0};
  for (int k0=0; k0<1024; k0+=64){
    #pragma unroll
    for (int i=0; i<2; i++){
      int r0 = wave*16 + i*8;
      GLOAD_LDS16(A + (size_t)(rb + r0 + srow)*1024 + k0 + schunk*8, &As[r0*64]);
    }
    #pragma unroll
    for (int i=0; i<4; i++){
      int r0 = wave*32 + i*8;
      GLOAD_LDS16(B + (size_t)(cb + r0 + srow)*1024 + k0 + schunk*8, &Bs[r0*64]);
    }
    __syncthreads();
    #pragma unroll
    for (int s=0; s<2; s++){
      int slot = (s*4 + quad) ^ (l16 & 7);
      bf16x8 a = *(const bf16x8*)&As[(wave*16 + l16)*64 + slot*8];
      #pragma unroll
      for (int g=0; g<8; g++){
        bf16x8 bv = *(const bf16x8*)&Bs[(g*16 + l16)*64 + slot*8];
        acc[g] = __builtin_amdgcn_mfma_f32_16x16x32_bf16(a, bv, acc[g], 0, 0, 0);
      }
    }
    __syncthreads();
  }
  int rowbase = rb + wave*16 + quad*4;
  if (MODE == 0){
    #pragma unroll
    for (int g=0; g<8; g++){
      int col = cb + g*16 + l16;
      float bs = bias[col];
      #pragma unroll
      for (int r=0; r<4; r++)
        Hout[(size_t)(rowbase + r)*1024 + col] = tobf(fmaxf(acc[g][r] + bs, 0.0f));
    }
  } else {
    float p0[4] = {0,0,0,0};
    #pragma unroll
    for (int g=0; g<8; g++){
      int col = cb + g*16 + l16;
      float bs = bias[col], wv = w3[col];
      #pragma unroll
      for (int r=0; r<4; r++)
        p0[r] += fmaxf(acc[g][r] + bs, 0.0f) * wv;
    }
    #pragma unroll
    for (int r=0; r<4; r++){
      #pragma unroll
      for (int m=1; m<16; m<<=1)
        p0[r] += __shfl_xor(p0[r], m, 16);
    }
    if (l16 == 0){
      #pragma unroll
      for (int r=0; r<4; r++)
        atomicAdd(&logit[rowbase + r], p0[r]);
    }
  }
}

// ---------------- 7. final sigmoid scores ----------------
__global__ void k_score(const float* __restrict__ logit, const float* __restrict__ b3,
                        const int* __restrict__ mcount, float* __restrict__ out, int chunk0){
  int i = blockIdx.x*blockDim.x + threadIdx.x;
  int r = chunk0 + i;
  int M = *mcount;
  if (r >= M) return;
  float lg = logit[i] + b3[0];
  out[4*NLINES + r] = 1.0f/(1.0f + expf(-lg));
}

extern "C" void kernel_launch(void* const* d_in, const int* in_sizes, int n_in,
                              void* d_out, int out_size, void* d_ws, size_t ws_size,
                              hipStream_t stream){
  const float* features = (const float*)d_in[0];
  const float* heatmaps = (const float*)d_in[1];
  const float* fc1_w    = (const float*)d_in[2];
  const float* fc1_b    = (const float*)d_in[3];
  const float* w1       = (const float*)d_in[4];
  const float* b1       = (const float*)d_in[5];
  const float* w2       = (const float*)d_in[6];
  const float* b2       = (const float*)d_in[7];
  const float* w3       = (const float*)d_in[8];
  const float* b3       = (const float*)d_in[9];
  float* out = (float*)d_out;

  char* ws = (char*)d_ws;
  size_t off = 0;
  auto alloc = [&](size_t bytes) -> void* {
    void* p = ws + off;
    off = (off + bytes + 255) & ~(size_t)255;
    return p;
  };
  float* lines     = (float*)alloc((size_t)NLINES*16);
  unsigned long long* cand = (unsigned long long*)alloc(CAND_CAP*8);
  // --- zero-init region: cand_count + bitmap (one async memset) ---
  int*      cand_count = (int*)alloc(4);
  unsigned* bitmap     = (unsigned*)alloc(BITWORDS*4);
  size_t zlen = (size_t)((char*)(bitmap + BITWORDS) - (char*)cand_count);
  float* junc      = (float*)alloc(KJ*2*4);
  int*   uid_list  = (int*)alloc((size_t)45056*4);
  int*   mcount    = (int*)alloc(4);
  short* loi       = (short*)alloc((size_t)HW*128*2);
  short* featT     = (short*)alloc((size_t)HW*256*2);
  short* fc1b16    = (short*)alloc((size_t)128*256*2);
  short* w1b       = (short*)alloc((size_t)1024*1024*2);
  short* w2b       = (short*)alloc((size_t)1024*1024*2);
  size_t fixed = off;

  // M <= KJ*(KJ-1)/2 = 44850 -> 45056 rows (64-aligned) max
  const int chunk_opts[4] = {45056, 22528, 11264, 5632};
  int CHUNK = 5632;
  for (int ci=0; ci<4; ci++){
    size_t need = fixed + (size_t)chunk_opts[ci]*1024*2*2 + (size_t)chunk_opts[ci]*4 + 1024;
    if (need <= ws_size){ CHUNK = chunk_opts[ci]; break; }
  }
  short* fbuf  = (short*)alloc((size_t)CHUNK*1024*2);
  short* h1buf = (short*)alloc((size_t)CHUNK*1024*2);
  float* logit = (float*)alloc((size_t)CHUNK*4);

  hipMemsetAsync(cand_count, 0, zlen, stream);
  k_front<<<4528, 256, 0, stream>>>(heatmaps, features, fc1_w, lines, cand,
                                    cand_count, featT, fc1b16, out);
  k_mid  <<<257, 1024, 0, stream>>>(cand, cand_count, heatmaps, junc, featT,
                                    fc1b16, fc1_b, loi);
  k_match<<<4288, 256, 0, stream>>>(lines, junc, bitmap, w1, w2, w1b, w2b);
  k_unique<<<1, 1024, 0, stream>>>(bitmap, uid_list, mcount);

  int nchunk = (45056 + CHUNK - 1) / CHUNK;
  for (int ci=0; ci<nchunk; ci++){
    int chunk0 = ci * CHUNK;
    k_sample<<<1024, 256, 0, stream>>>(out, uid_list, junc, loi, mcount, fbuf,
                                       logit, chunk0, CHUNK);
    dim3 g1(CHUNK/64, 8);
    k_mlp<0><<<g1, 256, 0, stream>>>(fbuf, w1b, b1, h1buf, nullptr,
                                     nullptr, mcount, chunk0);
    k_mlp<2><<<g1, 256, 0, stream>>>(h1buf, w2b, b2, nullptr, w3,
                                     logit, mcount, chunk0);
    k_score<<<(CHUNK+255)/256, 256, 0, stream>>>(logit, b3, mcount, out, chunk0);
  }
}

// Round 12
// 180.583 us; speedup vs baseline: 1.6085x; 1.1050x over previous
//
#include <hip/hip_runtime.h>
#include <math.h>

#define HH 128
#define WW 128
#define HW 16384
#define NLINES 49152
#define KJ 300
#define SENT 90000
#define THRESHV 0.008f
#define CAND_CAP 4096
#define BITWORDS 2816   // ceil(90000/32)

typedef __attribute__((ext_vector_type(8))) short bf16x8;
typedef __attribute__((ext_vector_type(4))) float f32x4;

__device__ __forceinline__ float sigm(float x){ return 1.0f/(1.0f+expf(-x)); }

__device__ __forceinline__ short tobf(float f){
  unsigned u = __float_as_uint(f);
  unsigned r = u + 0x7FFFu + ((u >> 16) & 1u);
  return (short)(r >> 16);
}
__device__ __forceinline__ float bflo(unsigned u){ return __uint_as_float(u << 16); }
__device__ __forceinline__ float bfhi(unsigned u){ return __uint_as_float(u & 0xFFFF0000u); }

#define GLOAD_LDS16(g, l) \
  __builtin_amdgcn_global_load_lds((const __attribute__((address_space(1))) void*)(g), \
                                   (__attribute__((address_space(3))) void*)(l), 16, 0, 0)

__device__ __forceinline__ float jloc_at(const float* hm, int idx){
  float h5 = hm[5*HW + idx], h6 = hm[6*HW + idx];
  float mx = fmaxf(h5,h6);
  float e5 = expf(h5-mx), e6 = expf(h6-mx);
  return e6/(e5+e6);
}

// ---- 1. fused front: prep + LDS-NMS | tcast | fc1 cast | zero d_out ----
__global__ __launch_bounds__(256) void k_front(const float* __restrict__ hm,
    const float* __restrict__ feat, const float* __restrict__ fc1w,
    float* __restrict__ lines, unsigned long long* __restrict__ cand,
    int* __restrict__ cand_count, short* __restrict__ featT, short* __restrict__ fc1b16,
    float* __restrict__ outZero){
  __shared__ float tile[32][33];
  __shared__ float jl[4][128];
  int b = blockIdx.x, t = threadIdx.x;
  if (b < 64){
    // ---- HAFM line decode (2 rows per block) ----
    int i = b*256 + t;
    float h0 = hm[i], h1 = hm[HW+i], h2 = hm[2*HW+i], h3 = hm[3*HW+i], h4 = hm[4*HW+i];
    float a0 = sigm(h0), a1 = sigm(h1), a2 = sigm(h2);
    float dist = sigm(h3), bias = sigm(h4);
    const float PI = 3.14159265358979323846f;
    float ang0 = (a0-0.5f)*(2.0f*PI);
    float c0 = cosf(ang0), s0 = sinf(ang0);
    float t1 = tanf(a1*(0.5f*PI));
    float t2 = tanf(-a2*(0.5f*PI));
    int y = i >> 7, x = i & 127;
    float fx = (float)x, fy = (float)y;
    #pragma unroll
    for (int c=0;c<3;c++){
      float d = fminf(fmaxf(dist + bias*(float)(c-1), 0.0f), 1.0f);
      float ds = d*5.0f;
      float x1 = fminf(fmaxf((c0 - s0*t1)*ds + fx, 0.0f), 127.0f);
      float y1 = fminf(fmaxf((s0 + c0*t1)*ds + fy, 0.0f), 127.0f);
      float x2 = fminf(fmaxf((c0 - s0*t2)*ds + fx, 0.0f), 127.0f);
      float y2 = fminf(fmaxf((s0 + c0*t2)*ds + fy, 0.0f), 127.0f);
      ((float4*)lines)[c*HW + i] = make_float4(x1,y1,x2,y2);
    }
    // ---- jloc tile rows 2b-1 .. 2b+2, identical formula per pixel ----
    int y0 = 2*b;
    #pragma unroll
    for (int idx = t; idx < 512; idx += 256){
      int r = idx >> 7, xx = idx & 127;
      int yy = y0 - 1 + r;
      jl[r][xx] = (yy >= 0 && yy < HH) ? jloc_at(hm, yy*WW + xx) : -1e30f;
    }
    __syncthreads();
    int lr = 1 + (t >> 7);
    float v = jl[lr][x];
    float m = v;
    #pragma unroll
    for (int dy=-1; dy<=1; dy++){
      #pragma unroll
      for (int dx=-1; dx<=1; dx++){
        int nx = x + dx; if (nx < 0 || nx >= WW) continue;
        m = fmaxf(m, jl[lr+dy][nx]);
      }
    }
    if (v == m && v > THRESHV){
      int pos = atomicAdd(cand_count, 1);
      if (pos < CAND_CAP){
        unsigned int vb = __float_as_uint(v);
        cand[pos] = ((unsigned long long)vb << 32) | (unsigned long long)(0xFFFFFFFFu - (unsigned)i);
      }
    }
  } else if (b < 64 + 4096){
    // ---- transpose-cast features [256,HW] fp32 -> featT [HW,256] bf16 ----
    int idx = b - 64;
    int p0 = (idx & 511) * 32, c0 = (idx >> 9) * 32;
    int c  = t >> 3;
    int p4 = (t & 7) * 4;
    float4 v = *(const float4*)&feat[(size_t)(c0 + c)*HW + p0 + p4];
    tile[c][p4+0] = v.x; tile[c][p4+1] = v.y; tile[c][p4+2] = v.z; tile[c][p4+3] = v.w;
    __syncthreads();
    int p  = t >> 3;
    int cg = (t & 7) * 4;
    ushort4 o;
    o.x = (unsigned short)tobf(tile[cg+0][p]);
    o.y = (unsigned short)tobf(tile[cg+1][p]);
    o.z = (unsigned short)tobf(tile[cg+2][p]);
    o.w = (unsigned short)tobf(tile[cg+3][p]);
    *(ushort4*)&featT[(size_t)(p0 + p)*256 + c0 + cg] = o;
  } else if (b < 4288){
    int j = (b - 4160)*256 + t;   // < 32768
    fc1b16[j] = tobf(fc1w[j]);
  } else {
    // ---- zero d_out: 240 blocks x 256 threads x float4 = 245760 floats ----
    int j = (b - 4288)*256 + t;
    ((float4*)outZero)[j] = make_float4(0.f,0.f,0.f,0.f);
  }
}

// ---- 2. fused mid: histogram-select top-K (1 blk) | LOI GEMM (256 blks) ----
__global__ __launch_bounds__(1024) void k_mid(
    const unsigned long long* __restrict__ cand, const int* __restrict__ cand_count,
    const float* __restrict__ hm, float* __restrict__ junc,
    const short* __restrict__ featT, const short* __restrict__ fc1b16,
    const float* __restrict__ fc1b, short* __restrict__ loi){
  __shared__ __align__(16) char smem[CAND_CAP*8];   // 32 KB union
  __shared__ int wsum16[16];
  __shared__ int sBbin, sScnt;
  int b = blockIdx.x, t = threadIdx.x;
  if (b == 0){
    // keys: (value_bits<<32)|(~idx). All values positive => bits [62:52] of the
    // key (= value bits [30:20]) are order-monotone across bins.
    int* hist = (int*)smem;                                       // 8 KB
    unsigned long long* sel = (unsigned long long*)(smem + 8192); // 16 KB
    unsigned long long* sfull = (unsigned long long*)smem;        // 32 KB (fallback)
    int count = *cand_count; if (count > CAND_CAP) count = CAND_CAP;
    int need = count < KJ ? count : KJ;
    hist[t] = 0; hist[t + 1024] = 0;
    if (t == 0){ sScnt = 0; sBbin = -1; }
    __syncthreads();
    for (int i=t; i<count; i+=1024){
      int bin = (int)(cand[i] >> 52) & 0x7FF;
      atomicAdd(&hist[bin], 1);
    }
    __syncthreads();
    // suffix scan: A(bin) = #keys in bins > bin. Thread t owns bins 2t, 2t+1.
    int c0 = hist[2*t], c1 = hist[2*t+1];
    int pairv = c0 + c1;
    int v = pairv;
    #pragma unroll
    for (int d=1; d<64; d<<=1){
      int nv = __shfl_down(v, d, 64);
      if ((t & 63) + d < 64) v += nv;
    }
    if ((t & 63) == 0) wsum16[t >> 6] = v;
    __syncthreads();
    if (t < 16){
      int x = wsum16[t];
      #pragma unroll
      for (int d=1; d<16; d<<=1){
        int nv = __shfl_down(x, d, 16);
        if (t + d < 16) x += nv;
      }
      wsum16[t] = x;
    }
    __syncthreads();
    int w = t >> 6;
    int after = (w < 15) ? wsum16[w+1] : 0;
    int suf = v + after;            // keys in bins >= 2t
    int A_hi = suf - pairv;         // keys in bins > 2t+1
    int A_lo = A_hi + c1;           // keys in bins > 2t
    if (need > 0){
      if (A_hi < need && need <= A_hi + c1)      sBbin = 2*t+1;
      else if (A_lo < need && need <= A_lo + c0) sBbin = 2*t;
    }
    __syncthreads();
    int Bbin = sBbin;
    if (Bbin >= 0){
      for (int i=t; i<count; i+=1024){
        unsigned long long k = cand[i];
        int bin = (int)(k >> 52) & 0x7FF;
        if (bin >= Bbin){
          int p = atomicAdd(&sScnt, 1);
          if (p < 2048) sel[p] = k;
        }
      }
    }
    __syncthreads();
    int S = sScnt;
    bool fb = (S > 2048);
    if (!fb){
      int n2 = 512; while (n2 < S) n2 <<= 1;
      for (int i=t; i<n2; i+=1024) if (i >= S) sel[i] = 0ull;
      __syncthreads();
      for (int k=2; k<=n2; k<<=1){
        for (int j=k>>1; j>0; j>>=1){
          for (int i=t; i<n2; i+=1024){
            int ixj = i ^ j;
            if (ixj > i){
              unsigned long long a = sel[i], bb = sel[ixj];
              bool desc = ((i & k) == 0);
              if (desc ? (a < bb) : (a > bb)){ sel[i] = bb; sel[ixj] = a; }
            }
          }
          __syncthreads();
        }
      }
    } else {
      // adversarial-tie fallback: full sort (original path)
      int n2 = 512; while (n2 < count) n2 <<= 1;
      __syncthreads();
      for (int i=t; i<n2; i+=1024) sfull[i] = (i < count) ? cand[i] : 0ull;
      __syncthreads();
      for (int k=2; k<=n2; k<<=1){
        for (int j=k>>1; j>0; j>>=1){
          for (int i=t; i<n2; i+=1024){
            int ixj = i ^ j;
            if (ixj > i){
              unsigned long long a = sfull[i], bb = sfull[ixj];
              bool desc = ((i & k) == 0);
              if (desc ? (a < bb) : (a > bb)){ sfull[i] = bb; sfull[ixj] = a; }
            }
          }
          __syncthreads();
        }
      }
    }
    if (t < KJ){
      float jxv = 1e6f, jyv = 1e6f;
      if (t < count){
        unsigned long long kk = fb ? sfull[t] : sel[t];
        unsigned idx = 0xFFFFFFFFu - (unsigned)(kk & 0xFFFFFFFFull);
        int yy = (int)(idx >> 7), xx = (int)(idx & 127u);
        jxv = (float)xx + sigm(hm[7*HW + idx]);
        jyv = (float)yy + sigm(hm[8*HW + idx]);
      }
      junc[2*t] = jxv; junc[2*t+1] = jyv;
    }
  } else {
    // ---- LOI GEMM: featT[HW,256] @ fc1w[128,256]^T -> loi[HW,128] bf16 ----
    if (t >= 256) return;
    short* As = (short*)smem;            // 8 KB
    short* Bs = (short*)(smem + 8192);   // 16 KB
    int rb = (b - 1) * 64;
    int lane = t & 63, wave = t >> 6;
    int l16 = lane & 15, quad = lane >> 4;
    int srow = lane >> 3, schunk = (lane & 7) ^ srow;
    f32x4 acc[8];
    #pragma unroll
    for (int g=0; g<8; g++) acc[g] = (f32x4){0,0,0,0};
    for (int k0=0; k0<256; k0+=64){
      #pragma unroll
      for (int i=0; i<2; i++){
        int r0 = wave*16 + i*8;
        GLOAD_LDS16(featT + (size_t)(rb + r0 + srow)*256 + k0 + schunk*8, &As[r0*64]);
      }
      #pragma unroll
      for (int i=0; i<4; i++){
        int r0 = wave*32 + i*8;
        GLOAD_LDS16(fc1b16 + (size_t)(r0 + srow)*256 + k0 + schunk*8, &Bs[r0*64]);
      }
      __syncthreads();
      #pragma unroll
      for (int s2=0; s2<2; s2++){
        int slot = (s2*4 + quad) ^ (l16 & 7);
        bf16x8 a = *(const bf16x8*)&As[(wave*16 + l16)*64 + slot*8];
        #pragma unroll
        for (int g=0; g<8; g++){
          bf16x8 bv = *(const bf16x8*)&Bs[(g*16 + l16)*64 + slot*8];
          acc[g] = __builtin_amdgcn_mfma_f32_16x16x32_bf16(a, bv, acc[g], 0, 0, 0);
        }
      }
      __syncthreads();
    }
    int rowbase = rb + wave*16 + quad*4;
    #pragma unroll
    for (int g=0; g<8; g++){
      int col = g*16 + l16;
      float bs = fc1b[col];
      #pragma unroll
      for (int r=0; r<4; r++)
        loi[(size_t)(rowbase + r)*128 + col] = tobf(acc[g][r] + bs);
    }
  }
}

// ---- 3. match -> global bitmap | w1/w2 cast  (ZERO fences anywhere) ----
__global__ __launch_bounds__(256) void k_match(const float* __restrict__ lines,
    const float* __restrict__ junc, unsigned* __restrict__ bm,
    const float* __restrict__ w1, const float* __restrict__ w2,
    short* __restrict__ w1b, short* __restrict__ w2b){
  __shared__ float jx[KJ], jy[KJ];
  int b = blockIdx.x, t = threadIdx.x;
  if (b < 192){
    for (int k=t; k<KJ; k+=256){ jx[k] = junc[2*k]; jy[k] = junc[2*k+1]; }
    __syncthreads();
    int n = b*256 + t;
    float4 L = ((const float4*)lines)[n];
    float b1 = 1e30f, b2 = 1e30f; int j1 = 0, j2 = 0;
    #pragma unroll 4
    for (int k=0; k<KJ; k++){
      float dx1 = jx[k]-L.x, dy1 = jy[k]-L.y;
      float d1 = dx1*dx1 + dy1*dy1;
      float dx2 = jx[k]-L.z, dy2 = jy[k]-L.w;
      float d2 = dx2*dx2 + dy2*dy2;
      if (d1 < b1){ b1 = d1; j1 = k; }
      if (d2 < b2){ b2 = d2; j2 = k; }
    }
    int lo = min(j1,j2), hi = max(j1,j2);
    if (lo < hi){
      int id = lo*KJ + hi;
      atomicOr(&bm[id >> 5], 1u << (id & 31));   // device-scope atomic; kernel boundary gives visibility
    }
  } else {
    int j = (b - 192)*256 + t;   // < 1M
    w1b[j] = tobf(w1[j]);
    w2b[j] = tobf(w2[j]);
  }
}

// ---------------- 4. unique: scan 2816-word global bitmap (1 block) ----------
__global__ __launch_bounds__(1024) void k_unique(const unsigned* __restrict__ bm,
    int* __restrict__ uid_list, int* __restrict__ mcount){
  __shared__ int wsum[16];
  int t = threadIdx.x;
  int w0 = t*3;
  unsigned wv[3];
  int local = 0;
  #pragma unroll
  for (int i=0; i<3; i++){
    int w = w0 + i;
    wv[i] = (w < BITWORDS) ? bm[w] : 0u;
    local += __popc(wv[i]);
  }
  int v = local;
  #pragma unroll
  for (int d=1; d<64; d<<=1){
    int nv = __shfl_up(v, d, 64);
    if ((t & 63) >= d) v += nv;
  }
  if ((t & 63) == 63) wsum[t >> 6] = v;
  __syncthreads();
  if (t < 16){
    int x = wsum[t];
    #pragma unroll
    for (int d=1; d<16; d<<=1){
      int nv = __shfl_up(x, d, 16);
      if (t >= d) x += nv;
    }
    wsum[t] = x;
  }
  __syncthreads();
  int base = v - local + ((t >> 6) ? wsum[(t >> 6) - 1] : 0);
  #pragma unroll
  for (int i=0; i<3; i++){
    unsigned bits = wv[i];
    while (bits){
      int bb = __ffs(bits) - 1;
      uid_list[base++] = (w0 + i)*32 + bb;
      bits &= bits - 1;
    }
  }
  if (t == 1023) *mcount = wsum[15];
}

// ---- 5. sampling, 2 lines per block-iteration (+ coords write) ----
__global__ __launch_bounds__(256) void k_sample(float* __restrict__ out,
    const int* __restrict__ uid_list, const float* __restrict__ junc,
    const short* __restrict__ loi, const int* __restrict__ mcount,
    short* __restrict__ fbuf, float* __restrict__ logit, int chunk0, int chunk){
  __shared__ int4   sOffs[2][32];
  __shared__ float4 sWts[2][32];
  int M = *mcount;
  int t = threadIdx.x;
  int q  = t >> 6;
  int c2 = (t & 63) << 1;
  int lim = M - chunk0; if (lim > chunk) lim = chunk;
  for (int l0 = blockIdx.x*2; l0 < lim; l0 += gridDim.x*2){
    __syncthreads();          // protect LDS from previous iteration's readers
    if (t < 64){
      int pair = t >> 5, s = t & 31;
      int l = l0 + pair;
      if (l < lim){
        int r = chunk0 + l;
        int id = uid_list[r];
        int lo = id / KJ, hi = id % KJ;
        float2 P1 = ((const float2*)junc)[lo];
        float2 P2 = ((const float2*)junc)[hi];
        if (s == 0){
          ((float4*)out)[r] = make_float4(P1.x, P1.y, P2.x, P2.y);
          logit[l] = 0.0f;
        }
        float tt = (float)s * (1.0f/31.0f);
        float px = P1.x*tt + P2.x*(1.0f-tt);
        float py = P1.y*tt + P2.y*(1.0f-tt);
        px = fminf(fmaxf(px, 0.0f), 127.0f);
        py = fminf(fmaxf(py, 0.0f), 127.0f);
        float x0 = floorf(px), y0 = floorf(py);
        int x0i = (int)x0, y0i = (int)y0;
        int x1i = min(x0i+1, 127), y1i = min(y0i+1, 127);
        float wx = px - x0, wy = py - y0;
        sOffs[pair][s] = make_int4((y0i*WW + x0i)*128, (y0i*WW + x1i)*128,
                                   (y1i*WW + x0i)*128, (y1i*WW + x1i)*128);
        sWts[pair][s]  = make_float4((1.0f-wx)*(1.0f-wy), wx*(1.0f-wy),
                                     (1.0f-wx)*wy,        wx*wy);
      }
    }
    __syncthreads();
    #pragma unroll
    for (int pair=0; pair<2; pair++){
      int l = l0 + pair;
      if (l >= lim) break;
      float gl0=-1e30f, gl1=-1e30f, gh0=-1e30f, gh1=-1e30f;
      #pragma unroll
      for (int j=0; j<8; j++){
        int s = q*8 + j;
        int4 o   = sOffs[pair][s];
        float4 w = sWts[pair][s];
        unsigned u00 = *(const unsigned*)&loi[o.x + c2];
        unsigned u01 = *(const unsigned*)&loi[o.y + c2];
        unsigned u10 = *(const unsigned*)&loi[o.z + c2];
        unsigned u11 = *(const unsigned*)&loi[o.w + c2];
        float vlo = w.x*bflo(u00) + w.y*bflo(u01) + w.z*bflo(u10) + w.w*bflo(u11);
        float vhi = w.x*bfhi(u00) + w.y*bfhi(u01) + w.z*bfhi(u10) + w.w*bfhi(u11);
        if (j < 4){ gl0 = fmaxf(gl0, vlo); gh0 = fmaxf(gh0, vhi); }
        else      { gl1 = fmaxf(gl1, vlo); gh1 = fmaxf(gh1, vhi); }
      }
      unsigned plo = ((unsigned)(unsigned short)tobf(gl0)) | (((unsigned)(unsigned short)tobf(gl1)) << 16);
      unsigned phi = ((unsigned)(unsigned short)tobf(gh0)) | (((unsigned)(unsigned short)tobf(gh1)) << 16);
      *(unsigned*)&fbuf[(size_t)l*1024 + c2*8 + q*2]     = plo;
      *(unsigned*)&fbuf[(size_t)l*1024 + (c2+1)*8 + q*2] = phi;
    }
  }
}

// ---------------- 6. 64x128-tile MFMA MLP GEMM (no fences) ----------------
// MODE 0: Hout bf16 = relu(C + bias)
// MODE 2: logit += relu(C + bias).w3  (plain device atomics only)
template<int MODE>
__global__ __launch_bounds__(256) void k_mlp(const short* __restrict__ A,
    const short* __restrict__ B, const float* __restrict__ bias,
    short* __restrict__ Hout, const float* __restrict__ w3,
    float* __restrict__ logit, const int* __restrict__ mcount, int chunk0){
  int M = *mcount;
  int rb = blockIdx.x * 64;
  if (chunk0 + rb >= M) return;
  int cb = blockIdx.y * 128;
  __shared__ short As[64*64];    // 8 KB
  __shared__ short Bs[128*64];   // 16 KB
  int lane = threadIdx.x & 63, wave = threadIdx.x >> 6;
  int l16 = lane & 15, quad = lane >> 4;
  int srow = lane >> 3, schunk = (lane & 7) ^ srow;
  f32x4 acc[8];
  #pragma unroll
  for (int g=0; g<8; g++) acc[g] = (f32x4){0,0,0,0};
  for (int k0=0; k0<1024; k0+=64){
    #pragma unroll
    for (int i=0; i<2; i++){
      int r0 = wave*16 + i*8;
      GLOAD_LDS16(A + (size_t)(rb + r0 + srow)*1024 + k0 + schunk*8, &As[r0*64]);
    }
    #pragma unroll
    for (int i=0; i<4; i++){
      int r0 = wave*32 + i*8;
      GLOAD_LDS16(B + (size_t)(cb + r0 + srow)*1024 + k0 + schunk*8, &Bs[r0*64]);
    }
    __syncthreads();
    #pragma unroll
    for (int s=0; s<2; s++){
      int slot = (s*4 + quad) ^ (l16 & 7);
      bf16x8 a = *(const bf16x8*)&As[(wave*16 + l16)*64 + slot*8];
      #pragma unroll
      for (int g=0; g<8; g++){
        bf16x8 bv = *(const bf16x8*)&Bs[(g*16 + l16)*64 + slot*8];
        acc[g] = __builtin_amdgcn_mfma_f32_16x16x32_bf16(a, bv, acc[g], 0, 0, 0);
      }
    }
    __syncthreads();
  }
  int rowbase = rb + wave*16 + quad*4;
  if (MODE == 0){
    #pragma unroll
    for (int g=0; g<8; g++){
      int col = cb + g*16 + l16;
      float bs = bias[col];
      #pragma unroll
      for (int r=0; r<4; r++)
        Hout[(size_t)(rowbase + r)*1024 + col] = tobf(fmaxf(acc[g][r] + bs, 0.0f));
    }
  } else {
    float p0[4] = {0,0,0,0};
    #pragma unroll
    for (int g=0; g<8; g++){
      int col = cb + g*16 + l16;
      float bs = bias[col], wv = w3[col];
      #pragma unroll
      for (int r=0; r<4; r++)
        p0[r] += fmaxf(acc[g][r] + bs, 0.0f) * wv;
    }
    #pragma unroll
    for (int r=0; r<4; r++){
      #pragma unroll
      for (int m=1; m<16; m<<=1)
        p0[r] += __shfl_xor(p0[r], m, 16);
    }
    if (l16 == 0){
      #pragma unroll
      for (int r=0; r<4; r++)
        atomicAdd(&logit[rowbase + r], p0[r]);
    }
  }
}

// ---------------- 7. final sigmoid scores ----------------
__global__ void k_score(const float* __restrict__ logit, const float* __restrict__ b3,
                        const int* __restrict__ mcount, float* __restrict__ out, int chunk0){
  int i = blockIdx.x*blockDim.x + threadIdx.x;
  int r = chunk0 + i;
  int M = *mcount;
  if (r >= M) return;
  float lg = logit[i] + b3[0];
  out[4*NLINES + r] = 1.0f/(1.0f + expf(-lg));
}

extern "C" void kernel_launch(void* const* d_in, const int* in_sizes, int n_in,
                              void* d_out, int out_size, void* d_ws, size_t ws_size,
                              hipStream_t stream){
  const float* features = (const float*)d_in[0];
  const float* heatmaps = (const float*)d_in[1];
  const float* fc1_w    = (const float*)d_in[2];
  const float* fc1_b    = (const float*)d_in[3];
  const float* w1       = (const float*)d_in[4];
  const float* b1       = (const float*)d_in[5];
  const float* w2       = (const float*)d_in[6];
  const float* b2       = (const float*)d_in[7];
  const float* w3       = (const float*)d_in[8];
  const float* b3       = (const float*)d_in[9];
  float* out = (float*)d_out;

  char* ws = (char*)d_ws;
  size_t off = 0;
  auto alloc = [&](size_t bytes) -> void* {
    void* p = ws + off;
    off = (off + bytes + 255) & ~(size_t)255;
    return p;
  };
  float* lines     = (float*)alloc((size_t)NLINES*16);
  unsigned long long* cand = (unsigned long long*)alloc(CAND_CAP*8);
  // --- zero-init region: cand_count + bitmap (one async memset) ---
  int*      cand_count = (int*)alloc(4);
  unsigned* bitmap     = (unsigned*)alloc(BITWORDS*4);
  size_t zlen = (size_t)((char*)(bitmap + BITWORDS) - (char*)cand_count);
  float* junc      = (float*)alloc(KJ*2*4);
  int*   uid_list  = (int*)alloc((size_t)45056*4);
  int*   mcount    = (int*)alloc(4);
  short* loi       = (short*)alloc((size_t)HW*128*2);
  short* featT     = (short*)alloc((size_t)HW*256*2);
  short* fc1b16    = (short*)alloc((size_t)128*256*2);
  short* w1b       = (short*)alloc((size_t)1024*1024*2);
  short* w2b       = (short*)alloc((size_t)1024*1024*2);
  size_t fixed = off;

  // M <= KJ*(KJ-1)/2 = 44850 -> 45056 rows (64-aligned) max
  const int chunk_opts[4] = {45056, 22528, 11264, 5632};
  int CHUNK = 5632;
  for (int ci=0; ci<4; ci++){
    size_t need = fixed + (size_t)chunk_opts[ci]*1024*2*2 + (size_t)chunk_opts[ci]*4 + 1024;
    if (need <= ws_size){ CHUNK = chunk_opts[ci]; break; }
  }
  short* fbuf  = (short*)alloc((size_t)CHUNK*1024*2);
  short* h1buf = (short*)alloc((size_t)CHUNK*1024*2);
  float* logit = (float*)alloc((size_t)CHUNK*4);

  hipMemsetAsync(cand_count, 0, zlen, stream);
  k_front<<<4528, 256, 0, stream>>>(heatmaps, features, fc1_w, lines, cand,
                                    cand_count, featT, fc1b16, out);
  k_mid  <<<257, 1024, 0, stream>>>(cand, cand_count, heatmaps, junc, featT,
                                    fc1b16, fc1_b, loi);
  k_match<<<4288, 256, 0, stream>>>(lines, junc, bitmap, w1, w2, w1b, w2b);
  k_unique<<<1, 1024, 0, stream>>>(bitmap, uid_list, mcount);

  int nchunk = (45056 + CHUNK - 1) / CHUNK;
  for (int ci=0; ci<nchunk; ci++){
    int chunk0 = ci * CHUNK;
    k_sample<<<1024, 256, 0, stream>>>(out, uid_list, junc, loi, mcount, fbuf,
                                       logit, chunk0, CHUNK);
    dim3 g1(CHUNK/64, 8);
    k_mlp<0><<<g1, 256, 0, stream>>>(fbuf, w1b, b1, h1buf, nullptr,
                                     nullptr, mcount, chunk0);
    k_mlp<2><<<g1, 256, 0, stream>>>(h1buf, w2b, b2, nullptr, w3,
                                     logit, mcount, chunk0);
    k_score<<<(CHUNK+255)/256, 256, 0, stream>>>(logit, b3, mcount, out, chunk0);
  }
}